// Round 6
// baseline (487.383 us; speedup 1.0000x reference)
//
#include <hip/hip_runtime.h>
#include <hip/hip_bf16.h>
#include <math.h>

typedef __attribute__((ext_vector_type(8))) short  bf16x8;
typedef __attribute__((ext_vector_type(4))) float  f32x4;
typedef __attribute__((ext_vector_type(8))) unsigned short u16x8;

#define HID  128
#define BM   32
#define LROW 1024   // edge-kernel LDS row stride (bytes): hE|vff/h2|h1/x|P

__device__ __forceinline__ unsigned short f2bf(float f) {
    union { float f; unsigned u; } v; v.f = f;
    unsigned u = v.u;
    return (unsigned short)((u + 0x7fffu + ((u >> 16) & 1u)) >> 16);
}
__device__ __forceinline__ unsigned pkbf(float a, float b) {
    __hip_bfloat162 h2 = __float22bfloat162_rn(float2{a, b});
    union { __hip_bfloat162 h; unsigned u; } u; u.h = h2; return u.u;
}
__device__ __forceinline__ unsigned short bfr(float f) {
    __hip_bfloat16 h = __float2bfloat16(f);
    union { __hip_bfloat16 h; unsigned short s; } u; u.h = h; return u.s;
}
__device__ __forceinline__ float bf2f(unsigned short h) {
    union { unsigned u; float f; } v; v.u = ((unsigned)h) << 16;
    return v.f;
}
// tanh-form GELU: max |diff vs exact| ~3e-4
__device__ __forceinline__ float geluf(float x) {
    float x2 = x * x;
    float u  = __builtin_fmaf(0.044715f * x2, x, x);
    float e  = __builtin_amdgcn_exp2f(u * 2.30220795f);
    return x * e * __builtin_amdgcn_rcpf(e + 1.0f);
}

// ---------------- weight prep ----------------
// wa  = W11 rows   0..127 (hV-src part),  transposed bf16 [128n][128k]
// wc  = W11 rows 256..383 (hV-dst part),  transposed bf16 [128n][128k]
// wbd = W11 rows 128..255 (hE) ++ 384..511 (vff), transposed bf16 [128n][256k]
__global__ void prep_weights(const float* __restrict__ W11, const float* __restrict__ W12,
                             const float* __restrict__ W13,
                             unsigned short* __restrict__ wa, unsigned short* __restrict__ wc,
                             unsigned short* __restrict__ wbd,
                             unsigned short* __restrict__ w12t, unsigned short* __restrict__ w13t) {
    int idx = blockIdx.x * 256 + threadIdx.x;
    if (idx < 16384) {
        int k = idx >> 7, n = idx & 127;
        wa[n * 128 + k] = f2bf(W11[k * 128 + n]);
    } else if (idx < 32768) {
        int j = idx - 16384; int k = j >> 7, n = j & 127;
        wc[n * 128 + k] = f2bf(W11[(256 + k) * 128 + n]);
    } else if (idx < 65536) {
        int j = idx - 32768; int k = j >> 7, n = j & 127;
        int row = (k < 128) ? (128 + k) : (256 + k);   // 256+k == 384+(k-128)
        wbd[n * 256 + k] = f2bf(W11[row * 128 + n]);
    } else if (idx < 81920) {
        int j = idx - 65536; int k = j >> 7, n = j & 127;
        w12t[n * 128 + k] = f2bf(W12[k * 128 + n]);
    } else if (idx < 98304) {
        int j = idx - 81920; int k = j >> 7, n = j & 127;
        w13t[n * 128 + k] = f2bf(W13[k * 128 + n]);
    }
}

// ---------------- P tables: P1 = hV@Wa + b11, P2 = hV@Wc (bf16) ----------------
__global__ __launch_bounds__(256, 4) void p_kernel(
    const float* __restrict__ hV,
    const unsigned short* __restrict__ wa, const unsigned short* __restrict__ wc,
    const float* __restrict__ b11,
    unsigned short* __restrict__ P1, unsigned short* __restrict__ P2, int nV)
{
    __shared__ __align__(16) char lds[BM * 512];
    const int tid = threadIdx.x, lane = tid & 63, wid = tid >> 6;
    const int lr = lane & 15, lh = lane >> 4;
    const int v0 = blockIdx.x * BM;

    {
        int r = tid >> 3, sub = tid & 7;
        int v = v0 + r; if (v >= nV) v = nV - 1;
        const float* sp = hV + (size_t)v * HID + sub * 16;
        f32x4 a0 = __builtin_nontemporal_load((const f32x4*)sp);
        f32x4 a1 = __builtin_nontemporal_load((const f32x4*)sp + 1);
        f32x4 a2 = __builtin_nontemporal_load((const f32x4*)sp + 2);
        f32x4 a3 = __builtin_nontemporal_load((const f32x4*)sp + 3);
        union { u16x8 s; unsigned u[4]; } pA, pB;
        pA.u[0] = pkbf(a0[0], a0[1]); pA.u[1] = pkbf(a0[2], a0[3]);
        pA.u[2] = pkbf(a1[0], a1[1]); pA.u[3] = pkbf(a1[2], a1[3]);
        pB.u[0] = pkbf(a2[0], a2[1]); pB.u[1] = pkbf(a2[2], a2[3]);
        pB.u[2] = pkbf(a3[0], a3[1]); pB.u[3] = pkbf(a3[2], a3[3]);
        int c0 = sub * 2, c1 = c0 + 1;
        int s0 = (c0 & 8) | ((c0 ^ r) & 7), s1 = (c1 & 8) | ((c1 ^ r) & 7);
        *(u16x8*)(lds + r * 512 + s0 * 16) = pA.s;
        *(u16x8*)(lds + r * 512 + s1 * 16) = pB.s;
    }
    __syncthreads();

    const int n0 = wid * 32 + lr, n1 = n0 + 16;
    f32x4 acc1[2][2], acc2[2][2];
#pragma unroll
    for (int j = 0; j < 2; ++j)
#pragma unroll
        for (int m = 0; m < 2; ++m) { acc1[j][m] = (f32x4){0,0,0,0}; acc2[j][m] = (f32x4){0,0,0,0}; }

    const unsigned short* a0p = wa + n0 * 128 + lh * 8;
    const unsigned short* a1p = wa + n1 * 128 + lh * 8;
    const unsigned short* c0p = wc + n0 * 128 + lh * 8;
    const unsigned short* c1p = wc + n1 * 128 + lh * 8;
#pragma unroll
    for (int kt = 0; kt < 4; ++kt) {
        bf16x8 ba0 = *(const bf16x8*)(a0p + kt * 32);
        bf16x8 ba1 = *(const bf16x8*)(a1p + kt * 32);
        bf16x8 bc0 = *(const bf16x8*)(c0p + kt * 32);
        bf16x8 bc1 = *(const bf16x8*)(c1p + kt * 32);
        int c = kt * 4 + lh;
#pragma unroll
        for (int m = 0; m < 2; ++m) {
            int row = m * 16 + lr;
            int sw  = (c & 8) | ((c ^ row) & 7);
            bf16x8 a = *(const bf16x8*)(lds + row * 512 + sw * 16);
            acc1[0][m] = __builtin_amdgcn_mfma_f32_16x16x32_bf16(a, ba0, acc1[0][m], 0, 0, 0);
            acc1[1][m] = __builtin_amdgcn_mfma_f32_16x16x32_bf16(a, ba1, acc1[1][m], 0, 0, 0);
            acc2[0][m] = __builtin_amdgcn_mfma_f32_16x16x32_bf16(a, bc0, acc2[0][m], 0, 0, 0);
            acc2[1][m] = __builtin_amdgcn_mfma_f32_16x16x32_bf16(a, bc1, acc2[1][m], 0, 0, 0);
        }
    }
    float bv0 = b11[n0], bv1 = b11[n1];
#pragma unroll
    for (int m = 0; m < 2; ++m)
#pragma unroll
        for (int i = 0; i < 4; ++i) {
            int row = m * 16 + lh * 4 + i;
            int v = v0 + row;
            if (v < nV) {
                size_t b = (size_t)v * HID;
                P1[b + n0] = bfr(acc1[0][m][i] + bv0);
                P1[b + n1] = bfr(acc1[1][m][i] + bv1);
                P2[b + n0] = bfr(acc2[0][m][i]);
                P2[b + n1] = bfr(acc2[1][m][i]);
            }
        }
}

// ---------------- fused edge MLP + residual + BN partials ----------------
// LDS row (1024B): [hE 0 | vff/h2 256 | h1/x 512 | P=P1[src]+P2[dst] 768],
// chunks XOR-swizzled within each 16-chunk region: slot = (c&8)|((c^row)&7).
// 32KB LDS + __launch_bounds__(256,5) -> 5 blocks/CU (160KB exactly), 20 waves/CU.
template <int XBF16>
__global__ __launch_bounds__(256, 5) void edge_mlp_kernel(
    const float* __restrict__ hE, const int* __restrict__ eidx,
    const float* __restrict__ vff,
    const unsigned short* __restrict__ P1, const unsigned short* __restrict__ P2,
    const unsigned short* __restrict__ wbd, const unsigned short* __restrict__ w12t,
    const unsigned short* __restrict__ w13t,
    const float* __restrict__ b12, const float* __restrict__ b13,
    float* __restrict__ psum, float* __restrict__ psumsq,
    float* __restrict__ xf32, unsigned short* __restrict__ xbf16, int E)
{
    __shared__ __align__(16) char lds[BM * LROW];
    const int tid = threadIdx.x, lane = tid & 63, wid = tid >> 6;
    const int lr = lane & 15, lh = lane >> 4;
    const int e0 = blockIdx.x * BM;
    const bool idx64 = ((eidx[1] | eidx[3] | eidx[5] | eidx[7]) == 0);
    const int n0 = wid * 32 + lr, n1 = n0 + 16;

    // ---- staging: hE/vff stream (f32->bf16) + P1[src]+P2[dst] folded gather ----
    {
        int r = tid >> 3, sub = tid & 7;
        int e = e0 + r;
        int sIdx = idx64 ? eidx[2 * e]       : eidx[e];
        int dIdx = idx64 ? eidx[2 * (E + e)] : eidx[E + e];

        const float* spE = hE  + (size_t)e * HID + sub * 16;
        const float* spV = vff + (size_t)e * HID + sub * 16;
        f32x4 h0 = __builtin_nontemporal_load((const f32x4*)spE);
        f32x4 h1 = __builtin_nontemporal_load((const f32x4*)spE + 1);
        f32x4 h2 = __builtin_nontemporal_load((const f32x4*)spE + 2);
        f32x4 h3 = __builtin_nontemporal_load((const f32x4*)spE + 3);
        f32x4 v0 = __builtin_nontemporal_load((const f32x4*)spV);
        f32x4 v1 = __builtin_nontemporal_load((const f32x4*)spV + 1);
        f32x4 v2 = __builtin_nontemporal_load((const f32x4*)spV + 2);
        f32x4 v3 = __builtin_nontemporal_load((const f32x4*)spV + 3);

        const unsigned short* p1p = P1 + (size_t)sIdx * HID + sub * 16;
        const unsigned short* p2p = P2 + (size_t)dIdx * HID + sub * 16;
        u16x8 g1a = *(const u16x8*)(p1p);
        u16x8 g1b = *(const u16x8*)(p1p + 8);
        u16x8 g2a = *(const u16x8*)(p2p);
        u16x8 g2b = *(const u16x8*)(p2p + 8);

        // fold P = P1[src] + P2[dst]
        union { u16x8 s; unsigned u[4]; } pf0, pf1;
#pragma unroll
        for (int j = 0; j < 4; ++j) {
            pf0.u[j] = pkbf(bf2f(g1a[2 * j])     + bf2f(g2a[2 * j]),
                            bf2f(g1a[2 * j + 1]) + bf2f(g2a[2 * j + 1]));
            pf1.u[j] = pkbf(bf2f(g1b[2 * j])     + bf2f(g2b[2 * j]),
                            bf2f(g1b[2 * j + 1]) + bf2f(g2b[2 * j + 1]));
        }
        int c0 = sub * 2, c1 = c0 + 1;
        int s0 = (c0 & 8) | ((c0 ^ r) & 7), s1 = (c1 & 8) | ((c1 ^ r) & 7);
        *(u16x8*)(lds + r * LROW + 768 + s0 * 16) = pf0.s;
        *(u16x8*)(lds + r * LROW + 768 + s1 * 16) = pf1.s;

        union { u16x8 s; unsigned u[4]; } cE0, cE1, cV0, cV1;
        cE0.u[0] = pkbf(h0[0], h0[1]); cE0.u[1] = pkbf(h0[2], h0[3]);
        cE0.u[2] = pkbf(h1[0], h1[1]); cE0.u[3] = pkbf(h1[2], h1[3]);
        cE1.u[0] = pkbf(h2[0], h2[1]); cE1.u[1] = pkbf(h2[2], h2[3]);
        cE1.u[2] = pkbf(h3[0], h3[1]); cE1.u[3] = pkbf(h3[2], h3[3]);
        cV0.u[0] = pkbf(v0[0], v0[1]); cV0.u[1] = pkbf(v0[2], v0[3]);
        cV0.u[2] = pkbf(v1[0], v1[1]); cV0.u[3] = pkbf(v1[2], v1[3]);
        cV1.u[0] = pkbf(v2[0], v2[1]); cV1.u[1] = pkbf(v2[2], v2[3]);
        cV1.u[2] = pkbf(v3[0], v3[1]); cV1.u[3] = pkbf(v3[2], v3[3]);
        *(u16x8*)(lds + r * LROW +   0 + s0 * 16) = cE0.s;
        *(u16x8*)(lds + r * LROW +   0 + s1 * 16) = cE1.s;
        *(u16x8*)(lds + r * LROW + 256 + s0 * 16) = cV0.s;
        *(u16x8*)(lds + r * LROW + 256 + s1 * 16) = cV1.s;
    }
    __syncthreads();

    f32x4 acc[2][2];
#pragma unroll
    for (int j = 0; j < 2; ++j)
#pragma unroll
        for (int m = 0; m < 2; ++m) acc[j][m] = (f32x4){0, 0, 0, 0};

    const unsigned short* w0p = wbd  + n0 * 256 + lh * 8;
    const unsigned short* w1p = wbd  + n1 * 256 + lh * 8;
    const unsigned short* q20 = w12t + n0 * 128 + lh * 8;
    const unsigned short* q21 = w12t + n1 * 128 + lh * 8;
    const unsigned short* q30 = w13t + n0 * 128 + lh * 8;
    const unsigned short* q31 = w13t + n1 * 128 + lh * 8;

    bf16x8 bA[4][2], bB[4][2], b2[4][2], b3[4][2];

#define PREF4(buf, p0, p1, base) \
    { _Pragma("unroll") for (int j = 0; j < 4; ++j) { \
        buf[j][0] = *(const bf16x8*)((p0) + ((base) + j) * 32); \
        buf[j][1] = *(const bf16x8*)((p1) + ((base) + j) * 32); } }

#define CONS4(buf, off) \
    { _Pragma("unroll") for (int j = 0; j < 4; ++j) { \
        int c = j * 4 + lh; \
        _Pragma("unroll") for (int m = 0; m < 2; ++m) { \
            int row = m * 16 + lr; \
            int sw  = (c & 8) | ((c ^ row) & 7); \
            bf16x8 a = *(const bf16x8*)(lds + row * LROW + (off) + sw * 16); \
            acc[0][m] = __builtin_amdgcn_mfma_f32_16x16x32_bf16(a, buf[j][0], acc[0][m], 0, 0, 0); \
            acc[1][m] = __builtin_amdgcn_mfma_f32_16x16x32_bf16(a, buf[j][1], acc[1][m], 0, 0, 0); } } }

    // ---- GEMM1: [32x256] @ [256x128] ----
    PREF4(bA, w0p, w1p, 0)
    PREF4(bB, w0p, w1p, 4)
    CONS4(bA, 0)                 // hE half
    PREF4(b2, q20, q21, 0)
    CONS4(bB, 256)               // vff half

    // ---- GELU1: + P (b11 folded into P1), h1 -> region 512 ----
#pragma unroll
    for (int m = 0; m < 2; ++m)
#pragma unroll
        for (int i = 0; i < 4; ++i) {
            int row = m * 16 + lh * 4 + i;
            int ch0 = n0 >> 3, ch1 = n1 >> 3;
            int s0 = (ch0 & 8) | ((ch0 ^ row) & 7);
            int s1 = (ch1 & 8) | ((ch1 ^ row) & 7);
            float p0 = bf2f(*(const unsigned short*)(lds + row * LROW + 768 + s0 * 16 + (n0 & 7) * 2));
            float p1 = bf2f(*(const unsigned short*)(lds + row * LROW + 768 + s1 * 16 + (n1 & 7) * 2));
            float v0 = geluf(acc[0][m][i] + p0);
            float v1 = geluf(acc[1][m][i] + p1);
            *(unsigned short*)(lds + row * LROW + 512 + s0 * 16 + (n0 & 7) * 2) = bfr(v0);
            *(unsigned short*)(lds + row * LROW + 512 + s1 * 16 + (n1 & 7) * 2) = bfr(v1);
        }
    PREF4(b3, q30, q31, 0)
    __syncthreads();

    // ---- GEMM2 ----
#pragma unroll
    for (int j = 0; j < 2; ++j)
#pragma unroll
        for (int m = 0; m < 2; ++m) acc[j][m] = (f32x4){0, 0, 0, 0};
    CONS4(b2, 512)
    {
        float bv0 = b12[n0], bv1 = b12[n1];
#pragma unroll
        for (int m = 0; m < 2; ++m)
#pragma unroll
            for (int i = 0; i < 4; ++i) {
                int row = m * 16 + lh * 4 + i;
                int ch0 = n0 >> 3, ch1 = n1 >> 3;
                int s0 = (ch0 & 8) | ((ch0 ^ row) & 7);
                int s1 = (ch1 & 8) | ((ch1 ^ row) & 7);
                float v0 = geluf(acc[0][m][i] + bv0);
                float v1 = geluf(acc[1][m][i] + bv1);
                *(unsigned short*)(lds + row * LROW + 256 + s0 * 16 + (n0 & 7) * 2) = bfr(v0);
                *(unsigned short*)(lds + row * LROW + 256 + s1 * 16 + (n1 & 7) * 2) = bfr(v1);
            }
    }
    __syncthreads();

    // ---- GEMM3 ----
#pragma unroll
    for (int j = 0; j < 2; ++j)
#pragma unroll
        for (int m = 0; m < 2; ++m) acc[j][m] = (f32x4){0, 0, 0, 0};
    CONS4(b3, 256)

    // ---- epilogue: +b13 +hE residual, BN partials, x -> region 512 ----
    {
        float bv0 = b13[n0], bv1 = b13[n1];
        float s0a = 0.f, q0a = 0.f, s1a = 0.f, q1a = 0.f;
#pragma unroll
        for (int m = 0; m < 2; ++m)
#pragma unroll
            for (int i = 0; i < 4; ++i) {
                int row = m * 16 + lh * 4 + i;
                int ch0 = n0 >> 3, ch1 = n1 >> 3;
                int s0 = (ch0 & 8) | ((ch0 ^ row) & 7);
                int s1 = (ch1 & 8) | ((ch1 ^ row) & 7);
                float he0 = bf2f(*(const unsigned short*)(lds + row * LROW + s0 * 16 + (n0 & 7) * 2));
                float he1 = bf2f(*(const unsigned short*)(lds + row * LROW + s1 * 16 + (n1 & 7) * 2));
                float x0 = acc[0][m][i] + bv0 + he0;
                float x1 = acc[1][m][i] + bv1 + he1;
                s0a += x0; q0a += x0 * x0;
                s1a += x1; q1a += x1 * x1;
                *(unsigned short*)(lds + row * LROW + 512 + s0 * 16 + (n0 & 7) * 2) = bfr(x0);
                *(unsigned short*)(lds + row * LROW + 512 + s1 * 16 + (n1 & 7) * 2) = bfr(x1);
            }
        s0a += __shfl_xor(s0a, 16); s0a += __shfl_xor(s0a, 32);
        q0a += __shfl_xor(q0a, 16); q0a += __shfl_xor(q0a, 32);
        s1a += __shfl_xor(s1a, 16); s1a += __shfl_xor(s1a, 32);
        q1a += __shfl_xor(q1a, 16); q1a += __shfl_xor(q1a, 32);
        if (lane < 16) {
            size_t base = (size_t)blockIdx.x * HID;
            psum[base + n0]   = s0a;
            psum[base + n1]   = s1a;
            psumsq[base + n0] = q0a;
            psumsq[base + n1] = q1a;
        }
    }
    __syncthreads();

    // ---- coalesced x write (16B/lane) ----
    {
        int r = tid >> 3, sub = tid & 7;
        int c0 = sub * 2, c1 = c0 + 1;
        int s0 = (c0 & 8) | ((c0 ^ r) & 7), s1 = (c1 & 8) | ((c1 ^ r) & 7);
        u16x8 X0 = *(const u16x8*)(lds + r * LROW + 512 + s0 * 16);
        u16x8 X1 = *(const u16x8*)(lds + r * LROW + 512 + s1 * 16);
        size_t base = (size_t)(e0 + r) * HID;
        if (XBF16) {
            __builtin_nontemporal_store(X0, (u16x8*)(xbf16 + base + c0 * 8));
            __builtin_nontemporal_store(X1, (u16x8*)(xbf16 + base + c1 * 8));
        } else {
            f32x4 o0, o1, o2, o3;
#pragma unroll
            for (int e = 0; e < 4; ++e) {
                o0[e] = bf2f(X0[e]); o1[e] = bf2f(X0[4 + e]);
                o2[e] = bf2f(X1[e]); o3[e] = bf2f(X1[4 + e]);
            }
            __builtin_nontemporal_store(o0, (f32x4*)(xf32 + base + c0 * 8));
            __builtin_nontemporal_store(o1, (f32x4*)(xf32 + base + c0 * 8 + 4));
            __builtin_nontemporal_store(o2, (f32x4*)(xf32 + base + c1 * 8));
            __builtin_nontemporal_store(o3, (f32x4*)(xf32 + base + c1 * 8 + 4));
        }
    }
}

// ---------------- BN stats ----------------
__global__ void bn_stats_kernel(const float* __restrict__ psum, const float* __restrict__ psumsq,
                                const float* __restrict__ gamma, const float* __restrict__ beta,
                                float* __restrict__ params, int nblk, float invE) {
    int c = blockIdx.x;
    float s = 0.f, q = 0.f;
    for (int i = threadIdx.x; i < nblk; i += 256) {
        s += psum[(size_t)i * 128 + c];
        q += psumsq[(size_t)i * 128 + c];
    }
#pragma unroll
    for (int o = 1; o < 64; o <<= 1) { s += __shfl_xor(s, o); q += __shfl_xor(q, o); }
    __shared__ float as[4], aq[4];
    int w = threadIdx.x >> 6;
    if ((threadIdx.x & 63) == 0) { as[w] = s; aq[w] = q; }
    __syncthreads();
    if (threadIdx.x == 0) {
        float S = as[0] + as[1] + as[2] + as[3];
        float Q = aq[0] + aq[1] + aq[2] + aq[3];
        float mean = S * invE;
        float var  = Q * invE - mean * mean;
        float sc   = gamma[c] * rsqrtf(var + 1e-5f);
        params[c]       = sc;
        params[128 + c] = beta[c] - mean * sc;
    }
}

// ---------------- BN apply ----------------
__global__ void bn_apply_bf16(const unsigned short* __restrict__ x, float* __restrict__ out,
                              const float* __restrict__ params, int total8) {
    __shared__ float sc[128], sh[128];
    if (threadIdx.x < 128) { sc[threadIdx.x] = params[threadIdx.x]; sh[threadIdx.x] = params[128 + threadIdx.x]; }
    __syncthreads();
    int stride = gridDim.x * blockDim.x;
    for (int i = blockIdx.x * blockDim.x + threadIdx.x; i < total8; i += stride) {
        size_t base = (size_t)i * 8;
        u16x8 v = __builtin_nontemporal_load((const u16x8*)(x + base));
        int c0 = (int)(base & 127);
        f32x4 o0, o1;
#pragma unroll
        for (int e = 0; e < 4; ++e) o0[e] = bf2f(v[e]) * sc[c0 + e] + sh[c0 + e];
#pragma unroll
        for (int e = 0; e < 4; ++e) o1[e] = bf2f(v[4 + e]) * sc[c0 + 4 + e] + sh[c0 + 4 + e];
        __builtin_nontemporal_store(o0, (f32x4*)(out + base));
        __builtin_nontemporal_store(o1, (f32x4*)(out + base + 4));
    }
}

__global__ void bn_apply_f32(float* __restrict__ x, const float* __restrict__ params, int total4) {
    __shared__ float sc[128], sh[128];
    if (threadIdx.x < 128) { sc[threadIdx.x] = params[threadIdx.x]; sh[threadIdx.x] = params[128 + threadIdx.x]; }
    __syncthreads();
    int stride = gridDim.x * blockDim.x;
    for (int i = blockIdx.x * blockDim.x + threadIdx.x; i < total4; i += stride) {
        size_t base = (size_t)i * 4;
        f32x4 v = *(f32x4*)(x + base);
        int c0 = (int)(base & 127);
#pragma unroll
        for (int e = 0; e < 4; ++e) v[e] = v[e] * sc[c0 + e] + sh[c0 + e];
        *(f32x4*)(x + base) = v;
    }
}

extern "C" void kernel_launch(void* const* d_in, const int* in_sizes, int n_in,
                              void* d_out, int out_size, void* d_ws, size_t ws_size,
                              hipStream_t stream) {
    const float* hV    = (const float*)d_in[0];
    const float* hE    = (const float*)d_in[1];
    const int*   eidx  = (const int*)d_in[2];
    const float* vff   = (const float*)d_in[4];
    const float* W11   = (const float*)d_in[5];
    const float* b11   = (const float*)d_in[6];
    const float* W12   = (const float*)d_in[7];
    const float* b12   = (const float*)d_in[8];
    const float* W13   = (const float*)d_in[9];
    const float* b13   = (const float*)d_in[10];
    const float* gamma = (const float*)d_in[11];
    const float* beta  = (const float*)d_in[12];

    const int nV    = in_sizes[0] / HID;          // 50000
    const int E     = in_sizes[1] / HID;          // 400000
    const int nblk  = E / BM;                     // 12500
    const int nblkV = (nV + BM - 1) / BM;         // 1563
    const int nVp   = nblkV * BM;                 // padded node rows

    float* params = (float*)d_ws;                           // 256 f32
    unsigned short* wa   = (unsigned short*)(params + 256);
    unsigned short* wc   = wa   + 16384;
    unsigned short* wbd  = wc   + 16384;
    unsigned short* w12t = wbd  + 32768;
    unsigned short* w13t = w12t + 16384;
    float* psum   = (float*)(w13t + 16384);
    float* psumsq = psum + (size_t)nblk * HID;
    unsigned short* P1 = (unsigned short*)(psumsq + (size_t)nblk * HID);
    unsigned short* P2 = P1 + (size_t)nVp * HID;
    unsigned short* xbf = P2 + (size_t)nVp * HID;
    const size_t fixed = (size_t)((char*)xbf - (char*)d_ws);
    const bool useBf = ws_size >= fixed + (size_t)E * HID * 2;

    prep_weights<<<384, 256, 0, stream>>>(W11, W12, W13, wa, wc, wbd, w12t, w13t);
    p_kernel<<<nblkV, 256, 0, stream>>>(hV, wa, wc, b11, P1, P2, nV);

    if (useBf)
        edge_mlp_kernel<1><<<nblk, 256, 0, stream>>>(hE, eidx, vff, P1, P2, wbd, w12t, w13t,
                                                     b12, b13, psum, psumsq,
                                                     (float*)d_out, xbf, E);
    else
        edge_mlp_kernel<0><<<nblk, 256, 0, stream>>>(hE, eidx, vff, P1, P2, wbd, w12t, w13t,
                                                     b12, b13, psum, psumsq,
                                                     (float*)d_out, xbf, E);

    bn_stats_kernel<<<128, 256, 0, stream>>>(psum, psumsq, gamma, beta, params, nblk,
                                             1.0f / (float)E);

    if (useBf)
        bn_apply_bf16<<<2048, 256, 0, stream>>>(xbf, (float*)d_out, params, E * HID / 8);
    else
        bn_apply_f32<<<2048, 256, 0, stream>>>((float*)d_out, params, E * HID / 4);
}

// Round 7
// 445.294 us; speedup vs baseline: 1.0945x; 1.0945x over previous
//
#include <hip/hip_runtime.h>
#include <hip/hip_bf16.h>
#include <math.h>

typedef __attribute__((ext_vector_type(8))) short  bf16x8;
typedef __attribute__((ext_vector_type(4))) float  f32x4;
typedef __attribute__((ext_vector_type(8))) unsigned short u16x8;

#define HID  128
#define BM   32
#define LROW 1024   // edge-kernel LDS row stride (bytes): hE|vff/h2|h1/x|P

__device__ __forceinline__ unsigned short f2bf(float f) {
    union { float f; unsigned u; } v; v.f = f;
    unsigned u = v.u;
    return (unsigned short)((u + 0x7fffu + ((u >> 16) & 1u)) >> 16);
}
__device__ __forceinline__ unsigned pkbf(float a, float b) {
    __hip_bfloat162 h2 = __float22bfloat162_rn(float2{a, b});
    union { __hip_bfloat162 h; unsigned u; } u; u.h = h2; return u.u;
}
__device__ __forceinline__ unsigned short bfr(float f) {
    __hip_bfloat16 h = __float2bfloat16(f);
    union { __hip_bfloat16 h; unsigned short s; } u; u.h = h; return u.s;
}
__device__ __forceinline__ float bf2f(unsigned short h) {
    union { unsigned u; float f; } v; v.u = ((unsigned)h) << 16;
    return v.f;
}
// tanh-form GELU: max |diff vs exact| ~3e-4
__device__ __forceinline__ float geluf(float x) {
    float x2 = x * x;
    float u  = __builtin_fmaf(0.044715f * x2, x, x);
    float e  = __builtin_amdgcn_exp2f(u * 2.30220795f);
    return x * e * __builtin_amdgcn_rcpf(e + 1.0f);
}

// ---------------- weight prep ----------------
// wa  = W11 rows   0..127 (hV-src part),  transposed bf16 [128n][128k]
// wc  = W11 rows 256..383 (hV-dst part),  transposed bf16 [128n][128k]
// wbd = W11 rows 128..255 (hE) ++ 384..511 (vff), transposed bf16 [128n][256k]
__global__ void prep_weights(const float* __restrict__ W11, const float* __restrict__ W12,
                             const float* __restrict__ W13,
                             unsigned short* __restrict__ wa, unsigned short* __restrict__ wc,
                             unsigned short* __restrict__ wbd,
                             unsigned short* __restrict__ w12t, unsigned short* __restrict__ w13t) {
    int idx = blockIdx.x * 256 + threadIdx.x;
    if (idx < 16384) {
        int k = idx >> 7, n = idx & 127;
        wa[n * 128 + k] = f2bf(W11[k * 128 + n]);
    } else if (idx < 32768) {
        int j = idx - 16384; int k = j >> 7, n = j & 127;
        wc[n * 128 + k] = f2bf(W11[(256 + k) * 128 + n]);
    } else if (idx < 65536) {
        int j = idx - 32768; int k = j >> 7, n = j & 127;
        int row = (k < 128) ? (128 + k) : (256 + k);   // 256+k == 384+(k-128)
        wbd[n * 256 + k] = f2bf(W11[row * 128 + n]);
    } else if (idx < 81920) {
        int j = idx - 65536; int k = j >> 7, n = j & 127;
        w12t[n * 128 + k] = f2bf(W12[k * 128 + n]);
    } else if (idx < 98304) {
        int j = idx - 81920; int k = j >> 7, n = j & 127;
        w13t[n * 128 + k] = f2bf(W13[k * 128 + n]);
    }
}

// ---------------- P tables: P1 = hV@Wa + b11, P2 = hV@Wc (bf16) ----------------
__global__ __launch_bounds__(256, 4) void p_kernel(
    const float* __restrict__ hV,
    const unsigned short* __restrict__ wa, const unsigned short* __restrict__ wc,
    const float* __restrict__ b11,
    unsigned short* __restrict__ P1, unsigned short* __restrict__ P2, int nV)
{
    __shared__ __align__(16) char lds[BM * 512];
    const int tid = threadIdx.x, lane = tid & 63, wid = tid >> 6;
    const int lr = lane & 15, lh = lane >> 4;
    const int v0 = blockIdx.x * BM;

    {
        int r = tid >> 3, sub = tid & 7;
        int v = v0 + r; if (v >= nV) v = nV - 1;
        const float* sp = hV + (size_t)v * HID + sub * 16;
        f32x4 a0 = __builtin_nontemporal_load((const f32x4*)sp);
        f32x4 a1 = __builtin_nontemporal_load((const f32x4*)sp + 1);
        f32x4 a2 = __builtin_nontemporal_load((const f32x4*)sp + 2);
        f32x4 a3 = __builtin_nontemporal_load((const f32x4*)sp + 3);
        union { u16x8 s; unsigned u[4]; } pA, pB;
        pA.u[0] = pkbf(a0[0], a0[1]); pA.u[1] = pkbf(a0[2], a0[3]);
        pA.u[2] = pkbf(a1[0], a1[1]); pA.u[3] = pkbf(a1[2], a1[3]);
        pB.u[0] = pkbf(a2[0], a2[1]); pB.u[1] = pkbf(a2[2], a2[3]);
        pB.u[2] = pkbf(a3[0], a3[1]); pB.u[3] = pkbf(a3[2], a3[3]);
        int c0 = sub * 2, c1 = c0 + 1;
        int s0 = (c0 & 8) | ((c0 ^ r) & 7), s1 = (c1 & 8) | ((c1 ^ r) & 7);
        *(u16x8*)(lds + r * 512 + s0 * 16) = pA.s;
        *(u16x8*)(lds + r * 512 + s1 * 16) = pB.s;
    }
    __syncthreads();

    const int n0 = wid * 32 + lr, n1 = n0 + 16;
    f32x4 acc1[2][2], acc2[2][2];
#pragma unroll
    for (int j = 0; j < 2; ++j)
#pragma unroll
        for (int m = 0; m < 2; ++m) { acc1[j][m] = (f32x4){0,0,0,0}; acc2[j][m] = (f32x4){0,0,0,0}; }

    const unsigned short* a0p = wa + n0 * 128 + lh * 8;
    const unsigned short* a1p = wa + n1 * 128 + lh * 8;
    const unsigned short* c0p = wc + n0 * 128 + lh * 8;
    const unsigned short* c1p = wc + n1 * 128 + lh * 8;
#pragma unroll
    for (int kt = 0; kt < 4; ++kt) {
        bf16x8 ba0 = *(const bf16x8*)(a0p + kt * 32);
        bf16x8 ba1 = *(const bf16x8*)(a1p + kt * 32);
        bf16x8 bc0 = *(const bf16x8*)(c0p + kt * 32);
        bf16x8 bc1 = *(const bf16x8*)(c1p + kt * 32);
        int c = kt * 4 + lh;
#pragma unroll
        for (int m = 0; m < 2; ++m) {
            int row = m * 16 + lr;
            int sw  = (c & 8) | ((c ^ row) & 7);
            bf16x8 a = *(const bf16x8*)(lds + row * 512 + sw * 16);
            acc1[0][m] = __builtin_amdgcn_mfma_f32_16x16x32_bf16(a, ba0, acc1[0][m], 0, 0, 0);
            acc1[1][m] = __builtin_amdgcn_mfma_f32_16x16x32_bf16(a, ba1, acc1[1][m], 0, 0, 0);
            acc2[0][m] = __builtin_amdgcn_mfma_f32_16x16x32_bf16(a, bc0, acc2[0][m], 0, 0, 0);
            acc2[1][m] = __builtin_amdgcn_mfma_f32_16x16x32_bf16(a, bc1, acc2[1][m], 0, 0, 0);
        }
    }
    float bv0 = b11[n0], bv1 = b11[n1];
#pragma unroll
    for (int m = 0; m < 2; ++m)
#pragma unroll
        for (int i = 0; i < 4; ++i) {
            int row = m * 16 + lh * 4 + i;
            int v = v0 + row;
            if (v < nV) {
                size_t b = (size_t)v * HID;
                P1[b + n0] = bfr(acc1[0][m][i] + bv0);
                P1[b + n1] = bfr(acc1[1][m][i] + bv1);
                P2[b + n0] = bfr(acc2[0][m][i]);
                P2[b + n1] = bfr(acc2[1][m][i]);
            }
        }
}

// ---------------- fused edge MLP + residual + BN partials ----------------
// LDS row (1024B): [hE 0 | vff/h2 256 | h1/x 512 | P=P1[src]+P2[dst] 768],
// chunks XOR-swizzled within each 16-chunk region: slot = (c&8)|((c^row)&7).
// 32KB LDS + (256,5) -> 5 blocks/CU (160KB exactly), 20 waves/CU.
// Liveness kept < ~90 regs: 2-batch staging, only bA+bB live in GEMM1,
// b2/b3 loaded late (round-6 lesson: deep prefetch at (256,5) spills).
template <int XBF16>
__global__ __launch_bounds__(256, 5) void edge_mlp_kernel(
    const float* __restrict__ hE, const int* __restrict__ eidx,
    const float* __restrict__ vff,
    const unsigned short* __restrict__ P1, const unsigned short* __restrict__ P2,
    const unsigned short* __restrict__ wbd, const unsigned short* __restrict__ w12t,
    const unsigned short* __restrict__ w13t,
    const float* __restrict__ b12, const float* __restrict__ b13,
    float* __restrict__ psum, float* __restrict__ psumsq,
    float* __restrict__ xf32, unsigned short* __restrict__ xbf16, int E)
{
    __shared__ __align__(16) char lds[BM * LROW];
    const int tid = threadIdx.x, lane = tid & 63, wid = tid >> 6;
    const int lr = lane & 15, lh = lane >> 4;
    const int e0 = blockIdx.x * BM;
    const bool idx64 = ((eidx[1] | eidx[3] | eidx[5] | eidx[7]) == 0);
    const int n0 = wid * 32 + lr, n1 = n0 + 16;

    // ---- staging, two batches to cap liveness ----
    {
        int r = tid >> 3, sub = tid & 7;
        int e = e0 + r;
        int sIdx = idx64 ? eidx[2 * e]       : eidx[e];
        int dIdx = idx64 ? eidx[2 * (E + e)] : eidx[E + e];
        int c0 = sub * 2, c1 = c0 + 1;
        int s0 = (c0 & 8) | ((c0 ^ r) & 7), s1 = (c1 & 8) | ((c1 ^ r) & 7);

        // batch A: hE stream + P1 gather
        const float* spE = hE + (size_t)e * HID + sub * 16;
        f32x4 h0 = __builtin_nontemporal_load((const f32x4*)spE);
        f32x4 h1 = __builtin_nontemporal_load((const f32x4*)spE + 1);
        f32x4 h2 = __builtin_nontemporal_load((const f32x4*)spE + 2);
        f32x4 h3 = __builtin_nontemporal_load((const f32x4*)spE + 3);
        const unsigned short* p1p = P1 + (size_t)sIdx * HID + sub * 16;
        u16x8 g1a = *(const u16x8*)(p1p);
        u16x8 g1b = *(const u16x8*)(p1p + 8);
        {
            union { u16x8 s; unsigned u[4]; } cE0, cE1;
            cE0.u[0] = pkbf(h0[0], h0[1]); cE0.u[1] = pkbf(h0[2], h0[3]);
            cE0.u[2] = pkbf(h1[0], h1[1]); cE0.u[3] = pkbf(h1[2], h1[3]);
            cE1.u[0] = pkbf(h2[0], h2[1]); cE1.u[1] = pkbf(h2[2], h2[3]);
            cE1.u[2] = pkbf(h3[0], h3[1]); cE1.u[3] = pkbf(h3[2], h3[3]);
            *(u16x8*)(lds + r * LROW + 0 + s0 * 16) = cE0.s;
            *(u16x8*)(lds + r * LROW + 0 + s1 * 16) = cE1.s;
        }

        // batch B: vff stream + P2 gather, fold P
        const float* spV = vff + (size_t)e * HID + sub * 16;
        f32x4 v0 = __builtin_nontemporal_load((const f32x4*)spV);
        f32x4 v1 = __builtin_nontemporal_load((const f32x4*)spV + 1);
        f32x4 v2 = __builtin_nontemporal_load((const f32x4*)spV + 2);
        f32x4 v3 = __builtin_nontemporal_load((const f32x4*)spV + 3);
        const unsigned short* p2p = P2 + (size_t)dIdx * HID + sub * 16;
        u16x8 g2a = *(const u16x8*)(p2p);
        u16x8 g2b = *(const u16x8*)(p2p + 8);
        {
            union { u16x8 s; unsigned u[4]; } cV0, cV1, pf0, pf1;
            cV0.u[0] = pkbf(v0[0], v0[1]); cV0.u[1] = pkbf(v0[2], v0[3]);
            cV0.u[2] = pkbf(v1[0], v1[1]); cV0.u[3] = pkbf(v1[2], v1[3]);
            cV1.u[0] = pkbf(v2[0], v2[1]); cV1.u[1] = pkbf(v2[2], v2[3]);
            cV1.u[2] = pkbf(v3[0], v3[1]); cV1.u[3] = pkbf(v3[2], v3[3]);
            *(u16x8*)(lds + r * LROW + 256 + s0 * 16) = cV0.s;
            *(u16x8*)(lds + r * LROW + 256 + s1 * 16) = cV1.s;
#pragma unroll
            for (int j = 0; j < 4; ++j) {
                pf0.u[j] = pkbf(bf2f(g1a[2 * j])     + bf2f(g2a[2 * j]),
                                bf2f(g1a[2 * j + 1]) + bf2f(g2a[2 * j + 1]));
                pf1.u[j] = pkbf(bf2f(g1b[2 * j])     + bf2f(g2b[2 * j]),
                                bf2f(g1b[2 * j + 1]) + bf2f(g2b[2 * j + 1]));
            }
            *(u16x8*)(lds + r * LROW + 768 + s0 * 16) = pf0.s;
            *(u16x8*)(lds + r * LROW + 768 + s1 * 16) = pf1.s;
        }
    }
    __syncthreads();

    f32x4 acc[2][2];
#pragma unroll
    for (int j = 0; j < 2; ++j)
#pragma unroll
        for (int m = 0; m < 2; ++m) acc[j][m] = (f32x4){0, 0, 0, 0};

    const unsigned short* w0p = wbd  + n0 * 256 + lh * 8;
    const unsigned short* w1p = wbd  + n1 * 256 + lh * 8;
    const unsigned short* q20 = w12t + n0 * 128 + lh * 8;
    const unsigned short* q21 = w12t + n1 * 128 + lh * 8;
    const unsigned short* q30 = w13t + n0 * 128 + lh * 8;
    const unsigned short* q31 = w13t + n1 * 128 + lh * 8;

    bf16x8 bA[4][2], bB[4][2];

#define PREF4(buf, p0, p1, base) \
    { _Pragma("unroll") for (int j = 0; j < 4; ++j) { \
        buf[j][0] = *(const bf16x8*)((p0) + ((base) + j) * 32); \
        buf[j][1] = *(const bf16x8*)((p1) + ((base) + j) * 32); } }

#define CONS4(buf, off) \
    { _Pragma("unroll") for (int j = 0; j < 4; ++j) { \
        int c = j * 4 + lh; \
        _Pragma("unroll") for (int m = 0; m < 2; ++m) { \
            int row = m * 16 + lr; \
            int sw  = (c & 8) | ((c ^ row) & 7); \
            bf16x8 a = *(const bf16x8*)(lds + row * LROW + (off) + sw * 16); \
            acc[0][m] = __builtin_amdgcn_mfma_f32_16x16x32_bf16(a, buf[j][0], acc[0][m], 0, 0, 0); \
            acc[1][m] = __builtin_amdgcn_mfma_f32_16x16x32_bf16(a, buf[j][1], acc[1][m], 0, 0, 0); } } }

    // ---- GEMM1: [32x256] @ [256x128] (only bA+bB live) ----
    PREF4(bA, w0p, w1p, 0)
    PREF4(bB, w0p, w1p, 4)
    CONS4(bA, 0)                 // hE half
    CONS4(bB, 256)               // vff half

    // ---- b2 load overlaps GELU1 VALU ----
    PREF4(bA, q20, q21, 0)       // reuse bA storage for GEMM2 weights

    // ---- GELU1: + P (b11 folded into P1), h1 -> region 512 ----
#pragma unroll
    for (int m = 0; m < 2; ++m)
#pragma unroll
        for (int i = 0; i < 4; ++i) {
            int row = m * 16 + lh * 4 + i;
            int ch0 = n0 >> 3, ch1 = n1 >> 3;
            int s0 = (ch0 & 8) | ((ch0 ^ row) & 7);
            int s1 = (ch1 & 8) | ((ch1 ^ row) & 7);
            float p0 = bf2f(*(const unsigned short*)(lds + row * LROW + 768 + s0 * 16 + (n0 & 7) * 2));
            float p1 = bf2f(*(const unsigned short*)(lds + row * LROW + 768 + s1 * 16 + (n1 & 7) * 2));
            float v0 = geluf(acc[0][m][i] + p0);
            float v1 = geluf(acc[1][m][i] + p1);
            *(unsigned short*)(lds + row * LROW + 512 + s0 * 16 + (n0 & 7) * 2) = bfr(v0);
            *(unsigned short*)(lds + row * LROW + 512 + s1 * 16 + (n1 & 7) * 2) = bfr(v1);
        }
    PREF4(bB, q30, q31, 0)       // GEMM3 weights; latency hides under barrier+GEMM2
    __syncthreads();

    // ---- GEMM2 ----
#pragma unroll
    for (int j = 0; j < 2; ++j)
#pragma unroll
        for (int m = 0; m < 2; ++m) acc[j][m] = (f32x4){0, 0, 0, 0};
    CONS4(bA, 512)
    {
        float bv0 = b12[n0], bv1 = b12[n1];
#pragma unroll
        for (int m = 0; m < 2; ++m)
#pragma unroll
            for (int i = 0; i < 4; ++i) {
                int row = m * 16 + lh * 4 + i;
                int ch0 = n0 >> 3, ch1 = n1 >> 3;
                int s0 = (ch0 & 8) | ((ch0 ^ row) & 7);
                int s1 = (ch1 & 8) | ((ch1 ^ row) & 7);
                float v0 = geluf(acc[0][m][i] + bv0);
                float v1 = geluf(acc[1][m][i] + bv1);
                *(unsigned short*)(lds + row * LROW + 256 + s0 * 16 + (n0 & 7) * 2) = bfr(v0);
                *(unsigned short*)(lds + row * LROW + 256 + s1 * 16 + (n1 & 7) * 2) = bfr(v1);
            }
    }
    __syncthreads();

    // ---- GEMM3 ----
#pragma unroll
    for (int j = 0; j < 2; ++j)
#pragma unroll
        for (int m = 0; m < 2; ++m) acc[j][m] = (f32x4){0, 0, 0, 0};
    CONS4(bB, 256)

    // ---- epilogue: +b13 +hE residual, BN partials, x -> region 512 ----
    {
        float bv0 = b13[n0], bv1 = b13[n1];
        float s0a = 0.f, q0a = 0.f, s1a = 0.f, q1a = 0.f;
#pragma unroll
        for (int m = 0; m < 2; ++m)
#pragma unroll
            for (int i = 0; i < 4; ++i) {
                int row = m * 16 + lh * 4 + i;
                int ch0 = n0 >> 3, ch1 = n1 >> 3;
                int s0 = (ch0 & 8) | ((ch0 ^ row) & 7);
                int s1 = (ch1 & 8) | ((ch1 ^ row) & 7);
                float he0 = bf2f(*(const unsigned short*)(lds + row * LROW + s0 * 16 + (n0 & 7) * 2));
                float he1 = bf2f(*(const unsigned short*)(lds + row * LROW + s1 * 16 + (n1 & 7) * 2));
                float x0 = acc[0][m][i] + bv0 + he0;
                float x1 = acc[1][m][i] + bv1 + he1;
                s0a += x0; q0a += x0 * x0;
                s1a += x1; q1a += x1 * x1;
                *(unsigned short*)(lds + row * LROW + 512 + s0 * 16 + (n0 & 7) * 2) = bfr(x0);
                *(unsigned short*)(lds + row * LROW + 512 + s1 * 16 + (n1 & 7) * 2) = bfr(x1);
            }
        s0a += __shfl_xor(s0a, 16); s0a += __shfl_xor(s0a, 32);
        q0a += __shfl_xor(q0a, 16); q0a += __shfl_xor(q0a, 32);
        s1a += __shfl_xor(s1a, 16); s1a += __shfl_xor(s1a, 32);
        q1a += __shfl_xor(q1a, 16); q1a += __shfl_xor(q1a, 32);
        if (lane < 16) {
            size_t base = (size_t)blockIdx.x * HID;
            psum[base + n0]   = s0a;
            psum[base + n1]   = s1a;
            psumsq[base + n0] = q0a;
            psumsq[base + n1] = q1a;
        }
    }
    __syncthreads();

    // ---- coalesced x write (16B/lane) ----
    {
        int r = tid >> 3, sub = tid & 7;
        int c0 = sub * 2, c1 = c0 + 1;
        int s0 = (c0 & 8) | ((c0 ^ r) & 7), s1 = (c1 & 8) | ((c1 ^ r) & 7);
        u16x8 X0 = *(const u16x8*)(lds + r * LROW + 512 + s0 * 16);
        u16x8 X1 = *(const u16x8*)(lds + r * LROW + 512 + s1 * 16);
        size_t base = (size_t)(e0 + r) * HID;
        if (XBF16) {
            __builtin_nontemporal_store(X0, (u16x8*)(xbf16 + base + c0 * 8));
            __builtin_nontemporal_store(X1, (u16x8*)(xbf16 + base + c1 * 8));
        } else {
            f32x4 o0, o1, o2, o3;
#pragma unroll
            for (int e = 0; e < 4; ++e) {
                o0[e] = bf2f(X0[e]); o1[e] = bf2f(X0[4 + e]);
                o2[e] = bf2f(X1[e]); o3[e] = bf2f(X1[4 + e]);
            }
            __builtin_nontemporal_store(o0, (f32x4*)(xf32 + base + c0 * 8));
            __builtin_nontemporal_store(o1, (f32x4*)(xf32 + base + c0 * 8 + 4));
            __builtin_nontemporal_store(o2, (f32x4*)(xf32 + base + c1 * 8));
            __builtin_nontemporal_store(o3, (f32x4*)(xf32 + base + c1 * 8 + 4));
        }
    }
}

// ---------------- BN stats, two-stage coalesced ----------------
// stage1: 64 blocks x 256 thr; thread t owns channel t&127, row-group t>>7;
// rows r = blockIdx*2+g stepping 128 -> fully coalesced 512B row reads.
__global__ void bn_stats1(const float* __restrict__ psum, const float* __restrict__ psumsq,
                          float* __restrict__ part, int nblk) {
    int t = threadIdx.x;
    int c = t & 127, g = t >> 7;
    float s = 0.f, q = 0.f;
    for (int r = blockIdx.x * 2 + g; r < nblk; r += 128) {
        s += psum[(size_t)r * 128 + c];
        q += psumsq[(size_t)r * 128 + c];
    }
    __shared__ float ls[256], lq[256];
    ls[t] = s; lq[t] = q;
    __syncthreads();
    if (t < 128) {
        part[(size_t)blockIdx.x * 256 + c]       = ls[c] + ls[128 + c];
        part[(size_t)blockIdx.x * 256 + 128 + c] = lq[c] + lq[128 + c];
    }
}
__global__ void bn_stats2(const float* __restrict__ part,
                          const float* __restrict__ gamma, const float* __restrict__ beta,
                          float* __restrict__ params, float invE) {
    int c = threadIdx.x;
    if (c < 128) {
        float S = 0.f, Q = 0.f;
        for (int b = 0; b < 64; ++b) {
            S += part[(size_t)b * 256 + c];
            Q += part[(size_t)b * 256 + 128 + c];
        }
        float mean = S * invE;
        float var  = Q * invE - mean * mean;
        float sc   = gamma[c] * rsqrtf(var + 1e-5f);
        params[c]       = sc;
        params[128 + c] = beta[c] - mean * sc;
    }
}

// ---------------- BN apply ----------------
__global__ void bn_apply_bf16(const unsigned short* __restrict__ x, float* __restrict__ out,
                              const float* __restrict__ params, int total8) {
    __shared__ float sc[128], sh[128];
    if (threadIdx.x < 128) { sc[threadIdx.x] = params[threadIdx.x]; sh[threadIdx.x] = params[128 + threadIdx.x]; }
    __syncthreads();
    int stride = gridDim.x * blockDim.x;
    for (int i = blockIdx.x * blockDim.x + threadIdx.x; i < total8; i += stride) {
        size_t base = (size_t)i * 8;
        u16x8 v = __builtin_nontemporal_load((const u16x8*)(x + base));
        int c0 = (int)(base & 127);
        f32x4 o0, o1;
#pragma unroll
        for (int e = 0; e < 4; ++e) o0[e] = bf2f(v[e]) * sc[c0 + e] + sh[c0 + e];
#pragma unroll
        for (int e = 0; e < 4; ++e) o1[e] = bf2f(v[4 + e]) * sc[c0 + 4 + e] + sh[c0 + 4 + e];
        __builtin_nontemporal_store(o0, (f32x4*)(out + base));
        __builtin_nontemporal_store(o1, (f32x4*)(out + base + 4));
    }
}

__global__ void bn_apply_f32(float* __restrict__ x, const float* __restrict__ params, int total4) {
    __shared__ float sc[128], sh[128];
    if (threadIdx.x < 128) { sc[threadIdx.x] = params[threadIdx.x]; sh[threadIdx.x] = params[128 + threadIdx.x]; }
    __syncthreads();
    int stride = gridDim.x * blockDim.x;
    for (int i = blockIdx.x * blockDim.x + threadIdx.x; i < total4; i += stride) {
        size_t base = (size_t)i * 4;
        f32x4 v = *(f32x4*)(x + base);
        int c0 = (int)(base & 127);
#pragma unroll
        for (int e = 0; e < 4; ++e) v[e] = v[e] * sc[c0 + e] + sh[c0 + e];
        *(f32x4*)(x + base) = v;
    }
}

extern "C" void kernel_launch(void* const* d_in, const int* in_sizes, int n_in,
                              void* d_out, int out_size, void* d_ws, size_t ws_size,
                              hipStream_t stream) {
    const float* hV    = (const float*)d_in[0];
    const float* hE    = (const float*)d_in[1];
    const int*   eidx  = (const int*)d_in[2];
    const float* vff   = (const float*)d_in[4];
    const float* W11   = (const float*)d_in[5];
    const float* b11   = (const float*)d_in[6];
    const float* W12   = (const float*)d_in[7];
    const float* b12   = (const float*)d_in[8];
    const float* W13   = (const float*)d_in[9];
    const float* b13   = (const float*)d_in[10];
    const float* gamma = (const float*)d_in[11];
    const float* beta  = (const float*)d_in[12];

    const int nV    = in_sizes[0] / HID;          // 50000
    const int E     = in_sizes[1] / HID;          // 400000
    const int nblk  = E / BM;                     // 12500
    const int nblkV = (nV + BM - 1) / BM;         // 1563
    const int nVp   = nblkV * BM;                 // padded node rows

    float* params = (float*)d_ws;                           // 256 f32
    float* part   = params + 256;                           // 64*256 f32
    unsigned short* wa   = (unsigned short*)(part + 64 * 256);
    unsigned short* wc   = wa   + 16384;
    unsigned short* wbd  = wc   + 16384;
    unsigned short* w12t = wbd  + 32768;
    unsigned short* w13t = w12t + 16384;
    float* psum   = (float*)(w13t + 16384);
    float* psumsq = psum + (size_t)nblk * HID;
    unsigned short* P1 = (unsigned short*)(psumsq + (size_t)nblk * HID);
    unsigned short* P2 = P1 + (size_t)nVp * HID;
    unsigned short* xbf = P2 + (size_t)nVp * HID;
    const size_t fixed = (size_t)((char*)xbf - (char*)d_ws);
    const bool useBf = ws_size >= fixed + (size_t)E * HID * 2;

    prep_weights<<<384, 256, 0, stream>>>(W11, W12, W13, wa, wc, wbd, w12t, w13t);
    p_kernel<<<nblkV, 256, 0, stream>>>(hV, wa, wc, b11, P1, P2, nV);

    if (useBf)
        edge_mlp_kernel<1><<<nblk, 256, 0, stream>>>(hE, eidx, vff, P1, P2, wbd, w12t, w13t,
                                                     b12, b13, psum, psumsq,
                                                     (float*)d_out, xbf, E);
    else
        edge_mlp_kernel<0><<<nblk, 256, 0, stream>>>(hE, eidx, vff, P1, P2, wbd, w12t, w13t,
                                                     b12, b13, psum, psumsq,
                                                     (float*)d_out, xbf, E);

    bn_stats1<<<64, 256, 0, stream>>>(psum, psumsq, part, nblk);
    bn_stats2<<<1, 128, 0, stream>>>(part, gamma, beta, params, 1.0f / (float)E);

    if (useBf)
        bn_apply_bf16<<<2048, 256, 0, stream>>>(xbf, (float*)d_out, params, E * HID / 8);
    else
        bn_apply_f32<<<2048, 256, 0, stream>>>((float*)d_out, params, E * HID / 4);
}

// Round 8
// 423.884 us; speedup vs baseline: 1.1498x; 1.0505x over previous
//
#include <hip/hip_runtime.h>
#include <hip/hip_bf16.h>
#include <math.h>

typedef __attribute__((ext_vector_type(8))) short  bf16x8;
typedef __attribute__((ext_vector_type(4))) float  f32x4;
typedef __attribute__((ext_vector_type(8))) unsigned short u16x8;

#define HID  128
#define BM   32     // edges per tile; 2 tiles per block
#define LROW 1024   // LDS row stride: hE|vff/h2|h1/x|P

__device__ __forceinline__ unsigned short f2bf(float f) {
    union { float f; unsigned u; } v; v.f = f;
    unsigned u = v.u;
    return (unsigned short)((u + 0x7fffu + ((u >> 16) & 1u)) >> 16);
}
__device__ __forceinline__ unsigned pkbf(float a, float b) {
    __hip_bfloat162 h2 = __float22bfloat162_rn(float2{a, b});
    union { __hip_bfloat162 h; unsigned u; } u; u.h = h2; return u.u;
}
__device__ __forceinline__ unsigned short bfr(float f) {
    __hip_bfloat16 h = __float2bfloat16(f);
    union { __hip_bfloat16 h; unsigned short s; } u; u.h = h; return u.s;
}
__device__ __forceinline__ float bf2f(unsigned short h) {
    union { unsigned u; float f; } v; v.u = ((unsigned)h) << 16;
    return v.f;
}
// tanh-form GELU: max |diff vs exact| ~3e-4
__device__ __forceinline__ float geluf(float x) {
    float x2 = x * x;
    float u  = __builtin_fmaf(0.044715f * x2, x, x);
    float e  = __builtin_amdgcn_exp2f(u * 2.30220795f);
    return x * e * __builtin_amdgcn_rcpf(e + 1.0f);
}

// ---------------- weight prep ----------------
__global__ void prep_weights(const float* __restrict__ W11, const float* __restrict__ W12,
                             const float* __restrict__ W13,
                             unsigned short* __restrict__ wa, unsigned short* __restrict__ wc,
                             unsigned short* __restrict__ wbd,
                             unsigned short* __restrict__ w12t, unsigned short* __restrict__ w13t) {
    int idx = blockIdx.x * 256 + threadIdx.x;
    if (idx < 16384) {
        int k = idx >> 7, n = idx & 127;
        wa[n * 128 + k] = f2bf(W11[k * 128 + n]);
    } else if (idx < 32768) {
        int j = idx - 16384; int k = j >> 7, n = j & 127;
        wc[n * 128 + k] = f2bf(W11[(256 + k) * 128 + n]);
    } else if (idx < 65536) {
        int j = idx - 32768; int k = j >> 7, n = j & 127;
        int row = (k < 128) ? (128 + k) : (256 + k);
        wbd[n * 256 + k] = f2bf(W11[row * 128 + n]);
    } else if (idx < 81920) {
        int j = idx - 65536; int k = j >> 7, n = j & 127;
        w12t[n * 128 + k] = f2bf(W12[k * 128 + n]);
    } else if (idx < 98304) {
        int j = idx - 81920; int k = j >> 7, n = j & 127;
        w13t[n * 128 + k] = f2bf(W13[k * 128 + n]);
    }
}

// ---------------- P tables: P1 = hV@Wa + b11, P2 = hV@Wc (bf16) ----------------
__global__ __launch_bounds__(256, 4) void p_kernel(
    const float* __restrict__ hV,
    const unsigned short* __restrict__ wa, const unsigned short* __restrict__ wc,
    const float* __restrict__ b11,
    unsigned short* __restrict__ P1, unsigned short* __restrict__ P2, int nV)
{
    __shared__ __align__(16) char lds[BM * 512];
    const int tid = threadIdx.x, lane = tid & 63, wid = tid >> 6;
    const int lr = lane & 15, lh = lane >> 4;
    const int v0 = blockIdx.x * BM;

    {
        int r = tid >> 3, sub = tid & 7;
        int v = v0 + r; if (v >= nV) v = nV - 1;
        const float* sp = hV + (size_t)v * HID + sub * 16;
        f32x4 a0 = __builtin_nontemporal_load((const f32x4*)sp);
        f32x4 a1 = __builtin_nontemporal_load((const f32x4*)sp + 1);
        f32x4 a2 = __builtin_nontemporal_load((const f32x4*)sp + 2);
        f32x4 a3 = __builtin_nontemporal_load((const f32x4*)sp + 3);
        union { u16x8 s; unsigned u[4]; } pA, pB;
        pA.u[0] = pkbf(a0[0], a0[1]); pA.u[1] = pkbf(a0[2], a0[3]);
        pA.u[2] = pkbf(a1[0], a1[1]); pA.u[3] = pkbf(a1[2], a1[3]);
        pB.u[0] = pkbf(a2[0], a2[1]); pB.u[1] = pkbf(a2[2], a2[3]);
        pB.u[2] = pkbf(a3[0], a3[1]); pB.u[3] = pkbf(a3[2], a3[3]);
        int c0 = sub * 2, c1 = c0 + 1;
        int s0 = (c0 & 8) | ((c0 ^ r) & 7), s1 = (c1 & 8) | ((c1 ^ r) & 7);
        *(u16x8*)(lds + r * 512 + s0 * 16) = pA.s;
        *(u16x8*)(lds + r * 512 + s1 * 16) = pB.s;
    }
    __syncthreads();

    const int n0 = wid * 32 + lr, n1 = n0 + 16;
    f32x4 acc1[2][2], acc2[2][2];
#pragma unroll
    for (int j = 0; j < 2; ++j)
#pragma unroll
        for (int m = 0; m < 2; ++m) { acc1[j][m] = (f32x4){0,0,0,0}; acc2[j][m] = (f32x4){0,0,0,0}; }

    const unsigned short* a0p = wa + n0 * 128 + lh * 8;
    const unsigned short* a1p = wa + n1 * 128 + lh * 8;
    const unsigned short* c0p = wc + n0 * 128 + lh * 8;
    const unsigned short* c1p = wc + n1 * 128 + lh * 8;
#pragma unroll
    for (int kt = 0; kt < 4; ++kt) {
        bf16x8 ba0 = *(const bf16x8*)(a0p + kt * 32);
        bf16x8 ba1 = *(const bf16x8*)(a1p + kt * 32);
        bf16x8 bc0 = *(const bf16x8*)(c0p + kt * 32);
        bf16x8 bc1 = *(const bf16x8*)(c1p + kt * 32);
        int c = kt * 4 + lh;
#pragma unroll
        for (int m = 0; m < 2; ++m) {
            int row = m * 16 + lr;
            int sw  = (c & 8) | ((c ^ row) & 7);
            bf16x8 a = *(const bf16x8*)(lds + row * 512 + sw * 16);
            acc1[0][m] = __builtin_amdgcn_mfma_f32_16x16x32_bf16(a, ba0, acc1[0][m], 0, 0, 0);
            acc1[1][m] = __builtin_amdgcn_mfma_f32_16x16x32_bf16(a, ba1, acc1[1][m], 0, 0, 0);
            acc2[0][m] = __builtin_amdgcn_mfma_f32_16x16x32_bf16(a, bc0, acc2[0][m], 0, 0, 0);
            acc2[1][m] = __builtin_amdgcn_mfma_f32_16x16x32_bf16(a, bc1, acc2[1][m], 0, 0, 0);
        }
    }
    float bv0 = b11[n0], bv1 = b11[n1];
#pragma unroll
    for (int m = 0; m < 2; ++m)
#pragma unroll
        for (int i = 0; i < 4; ++i) {
            int row = m * 16 + lh * 4 + i;
            int v = v0 + row;
            if (v < nV) {
                size_t b = (size_t)v * HID;
                P1[b + n0] = bfr(acc1[0][m][i] + bv0);
                P1[b + n1] = bfr(acc1[1][m][i] + bv1);
                P2[b + n0] = bfr(acc2[0][m][i]);
                P2[b + n1] = bfr(acc2[1][m][i]);
            }
        }
}

// ---------------- fused edge MLP, TPB=2 pipelined ----------------
// LDS row (1024B): [hE 0 | vff/h2 256 | h1/x 512 | P 768], swizzle slot=(c&8)|((c^r)&7).
// (256,4): proven no-spill point. Tile B's global loads issued during tile A's
// GEMM2/3 so HBM stays busy during compute (round-7 analysis: 30% BW duty).
template <int XBF16>
__global__ __launch_bounds__(256, 4) void edge_mlp_kernel(
    const float* __restrict__ hE, const int* __restrict__ eidx,
    const float* __restrict__ vff,
    const unsigned short* __restrict__ P1, const unsigned short* __restrict__ P2,
    const unsigned short* __restrict__ wbd, const unsigned short* __restrict__ w12t,
    const unsigned short* __restrict__ w13t,
    const float* __restrict__ b12, const float* __restrict__ b13,
    float* __restrict__ psum, float* __restrict__ psumsq,
    float* __restrict__ xf32, unsigned short* __restrict__ xbf16, int E)
{
    __shared__ __align__(16) char lds[BM * LROW];
    const int tid = threadIdx.x, lane = tid & 63, wid = tid >> 6;
    const int lr = lane & 15, lh = lane >> 4;
    const int e0 = blockIdx.x * (2 * BM);
    const bool idx64 = ((eidx[1] | eidx[3] | eidx[5] | eidx[7]) == 0);
    const int n0 = wid * 32 + lr, n1 = n0 + 16;

    const int r = tid >> 3, sub = tid & 7;
    const int sc0 = sub * 2, sc1 = sc0 + 1;
    const int sl0 = (sc0 & 8) | ((sc0 ^ r) & 7), sl1 = (sc1 & 8) | ((sc1 ^ r) & 7);

    const float bv12_0 = b12[n0], bv12_1 = b12[n1];
    const float bv13_0 = b13[n0], bv13_1 = b13[n1];

    f32x4 A0, A1, A2, A3, B0, B1, B2, B3;   // staged hE / vff quads
    u16x8 G1A, G1B, G2A, G2B;               // staged P gathers
    int sIdx, dIdx;
    float s0a = 0.f, q0a = 0.f, s1a = 0.f, q1a = 0.f;
    f32x4 acc[2][2];
    bf16x8 bA[4][2], bB[4][2];

    const unsigned short* w0p = wbd  + n0 * 256 + lh * 8;
    const unsigned short* w1p = wbd  + n1 * 256 + lh * 8;
    const unsigned short* q20 = w12t + n0 * 128 + lh * 8;
    const unsigned short* q21 = w12t + n1 * 128 + lh * 8;
    const unsigned short* q30 = w13t + n0 * 128 + lh * 8;
    const unsigned short* q31 = w13t + n1 * 128 + lh * 8;

#define STAGE_EIDX(E0T) { int e = (E0T) + r; \
    sIdx = idx64 ? eidx[2 * e]       : eidx[e]; \
    dIdx = idx64 ? eidx[2 * (E + e)] : eidx[E + e]; }

#define ISSUE_EV(E0T) { int e = (E0T) + r; \
    const f32x4* pE = (const f32x4*)(hE  + (size_t)e * HID + sub * 16); \
    const f32x4* pV = (const f32x4*)(vff + (size_t)e * HID + sub * 16); \
    A0 = __builtin_nontemporal_load(pE + 0); A1 = __builtin_nontemporal_load(pE + 1); \
    A2 = __builtin_nontemporal_load(pE + 2); A3 = __builtin_nontemporal_load(pE + 3); \
    B0 = __builtin_nontemporal_load(pV + 0); B1 = __builtin_nontemporal_load(pV + 1); \
    B2 = __builtin_nontemporal_load(pV + 2); B3 = __builtin_nontemporal_load(pV + 3); }

#define ISSUE_P() { \
    const u16x8* p1 = (const u16x8*)(P1 + (size_t)sIdx * HID + sub * 16); \
    const u16x8* p2 = (const u16x8*)(P2 + (size_t)dIdx * HID + sub * 16); \
    G1A = p1[0]; G1B = p1[1]; G2A = p2[0]; G2B = p2[1]; }

#define WRITE_EV() { union { u16x8 s; unsigned u[4]; } cE0, cE1, cV0, cV1; \
    cE0.u[0] = pkbf(A0[0], A0[1]); cE0.u[1] = pkbf(A0[2], A0[3]); \
    cE0.u[2] = pkbf(A1[0], A1[1]); cE0.u[3] = pkbf(A1[2], A1[3]); \
    cE1.u[0] = pkbf(A2[0], A2[1]); cE1.u[1] = pkbf(A2[2], A2[3]); \
    cE1.u[2] = pkbf(A3[0], A3[1]); cE1.u[3] = pkbf(A3[2], A3[3]); \
    cV0.u[0] = pkbf(B0[0], B0[1]); cV0.u[1] = pkbf(B0[2], B0[3]); \
    cV0.u[2] = pkbf(B1[0], B1[1]); cV0.u[3] = pkbf(B1[2], B1[3]); \
    cV1.u[0] = pkbf(B2[0], B2[1]); cV1.u[1] = pkbf(B2[2], B2[3]); \
    cV1.u[2] = pkbf(B3[0], B3[1]); cV1.u[3] = pkbf(B3[2], B3[3]); \
    *(u16x8*)(lds + r * LROW +   0 + sl0 * 16) = cE0.s; \
    *(u16x8*)(lds + r * LROW +   0 + sl1 * 16) = cE1.s; \
    *(u16x8*)(lds + r * LROW + 256 + sl0 * 16) = cV0.s; \
    *(u16x8*)(lds + r * LROW + 256 + sl1 * 16) = cV1.s; }

#define WRITE_P() { union { u16x8 s; unsigned u[4]; } pf0, pf1; \
    _Pragma("unroll") for (int j = 0; j < 4; ++j) { \
        pf0.u[j] = pkbf(bf2f(G1A[2*j]) + bf2f(G2A[2*j]), bf2f(G1A[2*j+1]) + bf2f(G2A[2*j+1])); \
        pf1.u[j] = pkbf(bf2f(G1B[2*j]) + bf2f(G2B[2*j]), bf2f(G1B[2*j+1]) + bf2f(G2B[2*j+1])); } \
    *(u16x8*)(lds + r * LROW + 768 + sl0 * 16) = pf0.s; \
    *(u16x8*)(lds + r * LROW + 768 + sl1 * 16) = pf1.s; }

#define ACCZERO { _Pragma("unroll") for (int j = 0; j < 2; ++j) \
    _Pragma("unroll") for (int m = 0; m < 2; ++m) acc[j][m] = (f32x4){0, 0, 0, 0}; }

#define PREF4(buf, p0, p1, base) \
    { _Pragma("unroll") for (int j = 0; j < 4; ++j) { \
        buf[j][0] = *(const bf16x8*)((p0) + ((base) + j) * 32); \
        buf[j][1] = *(const bf16x8*)((p1) + ((base) + j) * 32); } }

#define CONS4(buf, off) \
    { _Pragma("unroll") for (int j = 0; j < 4; ++j) { \
        int c = j * 4 + lh; \
        _Pragma("unroll") for (int m = 0; m < 2; ++m) { \
            int row = m * 16 + lr; \
            int sw  = (c & 8) | ((c ^ row) & 7); \
            bf16x8 a = *(const bf16x8*)(lds + row * LROW + (off) + sw * 16); \
            acc[0][m] = __builtin_amdgcn_mfma_f32_16x16x32_bf16(a, buf[j][0], acc[0][m], 0, 0, 0); \
            acc[1][m] = __builtin_amdgcn_mfma_f32_16x16x32_bf16(a, buf[j][1], acc[1][m], 0, 0, 0); } } }

#define GELU1_PHASE() { _Pragma("unroll") for (int m = 0; m < 2; ++m) \
    _Pragma("unroll") for (int i = 0; i < 4; ++i) { \
        int row = m * 16 + lh * 4 + i; int ch0 = n0 >> 3, ch1 = n1 >> 3; \
        int t0 = (ch0 & 8) | ((ch0 ^ row) & 7), t1 = (ch1 & 8) | ((ch1 ^ row) & 7); \
        float p0 = bf2f(*(const unsigned short*)(lds + row * LROW + 768 + t0 * 16 + (n0 & 7) * 2)); \
        float p1 = bf2f(*(const unsigned short*)(lds + row * LROW + 768 + t1 * 16 + (n1 & 7) * 2)); \
        float v0 = geluf(acc[0][m][i] + p0), v1 = geluf(acc[1][m][i] + p1); \
        *(unsigned short*)(lds + row * LROW + 512 + t0 * 16 + (n0 & 7) * 2) = bfr(v0); \
        *(unsigned short*)(lds + row * LROW + 512 + t1 * 16 + (n1 & 7) * 2) = bfr(v1); } }

#define GELU2_PHASE() { _Pragma("unroll") for (int m = 0; m < 2; ++m) \
    _Pragma("unroll") for (int i = 0; i < 4; ++i) { \
        int row = m * 16 + lh * 4 + i; int ch0 = n0 >> 3, ch1 = n1 >> 3; \
        int t0 = (ch0 & 8) | ((ch0 ^ row) & 7), t1 = (ch1 & 8) | ((ch1 ^ row) & 7); \
        float v0 = geluf(acc[0][m][i] + bv12_0), v1 = geluf(acc[1][m][i] + bv12_1); \
        *(unsigned short*)(lds + row * LROW + 256 + t0 * 16 + (n0 & 7) * 2) = bfr(v0); \
        *(unsigned short*)(lds + row * LROW + 256 + t1 * 16 + (n1 & 7) * 2) = bfr(v1); } }

#define EPILOGUE_PHASE() { _Pragma("unroll") for (int m = 0; m < 2; ++m) \
    _Pragma("unroll") for (int i = 0; i < 4; ++i) { \
        int row = m * 16 + lh * 4 + i; int ch0 = n0 >> 3, ch1 = n1 >> 3; \
        int t0 = (ch0 & 8) | ((ch0 ^ row) & 7), t1 = (ch1 & 8) | ((ch1 ^ row) & 7); \
        float he0 = bf2f(*(const unsigned short*)(lds + row * LROW + t0 * 16 + (n0 & 7) * 2)); \
        float he1 = bf2f(*(const unsigned short*)(lds + row * LROW + t1 * 16 + (n1 & 7) * 2)); \
        float x0 = acc[0][m][i] + bv13_0 + he0; \
        float x1 = acc[1][m][i] + bv13_1 + he1; \
        s0a += x0; q0a += x0 * x0; s1a += x1; q1a += x1 * x1; \
        *(unsigned short*)(lds + row * LROW + 512 + t0 * 16 + (n0 & 7) * 2) = bfr(x0); \
        *(unsigned short*)(lds + row * LROW + 512 + t1 * 16 + (n1 & 7) * 2) = bfr(x1); } }

#define XWRITE_PHASE(E0T) { \
    u16x8 X0 = *(const u16x8*)(lds + r * LROW + 512 + sl0 * 16); \
    u16x8 X1 = *(const u16x8*)(lds + r * LROW + 512 + sl1 * 16); \
    size_t base = (size_t)((E0T) + r) * HID; \
    if (XBF16) { \
        __builtin_nontemporal_store(X0, (u16x8*)(xbf16 + base + sc0 * 8)); \
        __builtin_nontemporal_store(X1, (u16x8*)(xbf16 + base + sc1 * 8)); \
    } else { \
        f32x4 o0, o1, o2, o3; \
        _Pragma("unroll") for (int e = 0; e < 4; ++e) { \
            o0[e] = bf2f(X0[e]); o1[e] = bf2f(X0[4 + e]); \
            o2[e] = bf2f(X1[e]); o3[e] = bf2f(X1[4 + e]); } \
        __builtin_nontemporal_store(o0, (f32x4*)(xf32 + base + sc0 * 8)); \
        __builtin_nontemporal_store(o1, (f32x4*)(xf32 + base + sc0 * 8 + 4)); \
        __builtin_nontemporal_store(o2, (f32x4*)(xf32 + base + sc1 * 8)); \
        __builtin_nontemporal_store(o3, (f32x4*)(xf32 + base + sc1 * 8 + 4)); } }

    // ================= tile A =================
    STAGE_EIDX(e0); ISSUE_EV(e0); ISSUE_P();
    WRITE_EV(); WRITE_P();
    __syncthreads();

    ACCZERO;
    PREF4(bA, w0p, w1p, 0)
    PREF4(bB, w0p, w1p, 4)
    CONS4(bA, 0)
    CONS4(bB, 256)
    PREF4(bA, q20, q21, 0)
    GELU1_PHASE()
    PREF4(bB, q30, q31, 0)
    __syncthreads();

    ACCZERO;
    CONS4(bA, 512)
    GELU2_PHASE()
    STAGE_EIDX(e0 + BM); ISSUE_EV(e0 + BM);   // tile B streams: in flight over GEMM3+epilogue
    __syncthreads();

    ACCZERO;
    CONS4(bB, 256)
    ISSUE_P();                                 // tile B P gathers: hidden under epilogue
    EPILOGUE_PHASE()
    WRITE_P();                                 // region 768 dead since GELU1(A) -> safe
    __syncthreads();

    XWRITE_PHASE(e0)
    WRITE_EV()                                 // regions 0/256 dead after epilogue(A)+barrier
    PREF4(bA, w0p, w1p, 0)                     // reload GEMM1 weights (L2-hot)
    PREF4(bB, w0p, w1p, 4)
    __syncthreads();

    // ================= tile B =================
    ACCZERO;
    CONS4(bA, 0)
    CONS4(bB, 256)
    PREF4(bA, q20, q21, 0)
    GELU1_PHASE()
    PREF4(bB, q30, q31, 0)
    __syncthreads();

    ACCZERO;
    CONS4(bA, 512)
    GELU2_PHASE()
    __syncthreads();

    ACCZERO;
    CONS4(bB, 256)
    EPILOGUE_PHASE()
    __syncthreads();

    XWRITE_PHASE(e0 + BM)

    // ---- BN partials (both tiles accumulated) ----
    s0a += __shfl_xor(s0a, 16); s0a += __shfl_xor(s0a, 32);
    q0a += __shfl_xor(q0a, 16); q0a += __shfl_xor(q0a, 32);
    s1a += __shfl_xor(s1a, 16); s1a += __shfl_xor(s1a, 32);
    q1a += __shfl_xor(q1a, 16); q1a += __shfl_xor(q1a, 32);
    if (lane < 16) {
        size_t base = (size_t)blockIdx.x * HID;
        psum[base + n0]   = s0a;
        psum[base + n1]   = s1a;
        psumsq[base + n0] = q0a;
        psumsq[base + n1] = q1a;
    }
}

// ---------------- BN stats, two-stage coalesced ----------------
__global__ void bn_stats1(const float* __restrict__ psum, const float* __restrict__ psumsq,
                          float* __restrict__ part, int nblk) {
    int t = threadIdx.x;
    int c = t & 127, g = t >> 7;
    float s = 0.f, q = 0.f;
    for (int r = blockIdx.x * 2 + g; r < nblk; r += 128) {
        s += psum[(size_t)r * 128 + c];
        q += psumsq[(size_t)r * 128 + c];
    }
    __shared__ float ls[256], lq[256];
    ls[t] = s; lq[t] = q;
    __syncthreads();
    if (t < 128) {
        part[(size_t)blockIdx.x * 256 + c]       = ls[c] + ls[128 + c];
        part[(size_t)blockIdx.x * 256 + 128 + c] = lq[c] + lq[128 + c];
    }
}
__global__ void bn_stats2(const float* __restrict__ part,
                          const float* __restrict__ gamma, const float* __restrict__ beta,
                          float* __restrict__ params, float invE) {
    int c = threadIdx.x;
    if (c < 128) {
        float S = 0.f, Q = 0.f;
        for (int b = 0; b < 64; ++b) {
            S += part[(size_t)b * 256 + c];
            Q += part[(size_t)b * 256 + 128 + c];
        }
        float mean = S * invE;
        float var  = Q * invE - mean * mean;
        float sc   = gamma[c] * rsqrtf(var + 1e-5f);
        params[c]       = sc;
        params[128 + c] = beta[c] - mean * sc;
    }
}

// ---------------- BN apply ----------------
__global__ void bn_apply_bf16(const unsigned short* __restrict__ x, float* __restrict__ out,
                              const float* __restrict__ params, int total8) {
    __shared__ float sc[128], sh[128];
    if (threadIdx.x < 128) { sc[threadIdx.x] = params[threadIdx.x]; sh[threadIdx.x] = params[128 + threadIdx.x]; }
    __syncthreads();
    int stride = gridDim.x * blockDim.x;
    for (int i = blockIdx.x * blockDim.x + threadIdx.x; i < total8; i += stride) {
        size_t base = (size_t)i * 8;
        u16x8 v = __builtin_nontemporal_load((const u16x8*)(x + base));
        int c0 = (int)(base & 127);
        f32x4 o0, o1;
#pragma unroll
        for (int e = 0; e < 4; ++e) o0[e] = bf2f(v[e]) * sc[c0 + e] + sh[c0 + e];
#pragma unroll
        for (int e = 0; e < 4; ++e) o1[e] = bf2f(v[4 + e]) * sc[c0 + 4 + e] + sh[c0 + 4 + e];
        __builtin_nontemporal_store(o0, (f32x4*)(out + base));
        __builtin_nontemporal_store(o1, (f32x4*)(out + base + 4));
    }
}

__global__ void bn_apply_f32(float* __restrict__ x, const float* __restrict__ params, int total4) {
    __shared__ float sc[128], sh[128];
    if (threadIdx.x < 128) { sc[threadIdx.x] = params[threadIdx.x]; sh[threadIdx.x] = params[128 + threadIdx.x]; }
    __syncthreads();
    int stride = gridDim.x * blockDim.x;
    for (int i = blockIdx.x * blockDim.x + threadIdx.x; i < total4; i += stride) {
        size_t base = (size_t)i * 4;
        f32x4 v = *(f32x4*)(x + base);
        int c0 = (int)(base & 127);
#pragma unroll
        for (int e = 0; e < 4; ++e) v[e] = v[e] * sc[c0 + e] + sh[c0 + e];
        *(f32x4*)(x + base) = v;
    }
}

extern "C" void kernel_launch(void* const* d_in, const int* in_sizes, int n_in,
                              void* d_out, int out_size, void* d_ws, size_t ws_size,
                              hipStream_t stream) {
    const float* hV    = (const float*)d_in[0];
    const float* hE    = (const float*)d_in[1];
    const int*   eidx  = (const int*)d_in[2];
    const float* vff   = (const float*)d_in[4];
    const float* W11   = (const float*)d_in[5];
    const float* b11   = (const float*)d_in[6];
    const float* W12   = (const float*)d_in[7];
    const float* b12   = (const float*)d_in[8];
    const float* W13   = (const float*)d_in[9];
    const float* b13   = (const float*)d_in[10];
    const float* gamma = (const float*)d_in[11];
    const float* beta  = (const float*)d_in[12];

    const int nV    = in_sizes[0] / HID;          // 50000
    const int E     = in_sizes[1] / HID;          // 400000
    const int nblk  = E / (2 * BM);               // 6250 (64 edges/block)
    const int nblkV = (nV + BM - 1) / BM;
    const int nVp   = nblkV * BM;

    float* params = (float*)d_ws;                           // 256 f32
    float* part   = params + 256;                           // 64*256 f32
    unsigned short* wa   = (unsigned short*)(part + 64 * 256);
    unsigned short* wc   = wa   + 16384;
    unsigned short* wbd  = wc   + 16384;
    unsigned short* w12t = wbd  + 32768;
    unsigned short* w13t = w12t + 16384;
    float* psum   = (float*)(w13t + 16384);
    float* psumsq = psum + (size_t)nblk * HID;
    char*  after  = (char*)(psumsq + (size_t)nblk * HID);
    size_t off    = ((size_t)(after - (char*)d_ws) + 15) & ~(size_t)15;

    // bf16-x path: P tables live in d_out (dead before bn_apply overwrites it),
    // xbf16 in ws. Fallback: P in ws, x f32 straight to d_out.
    const bool useBf = ws_size >= off + (size_t)E * HID * 2;
    unsigned short *P1, *P2, *xbf = nullptr;
    if (useBf) {
        P1  = (unsigned short*)d_out;
        P2  = P1 + (size_t)nVp * HID;
        xbf = (unsigned short*)((char*)d_ws + off);
    } else {
        P1  = (unsigned short*)((char*)d_ws + off);
        P2  = P1 + (size_t)nVp * HID;
    }

    prep_weights<<<384, 256, 0, stream>>>(W11, W12, W13, wa, wc, wbd, w12t, w13t);
    p_kernel<<<nblkV, 256, 0, stream>>>(hV, wa, wc, b11, P1, P2, nV);

    if (useBf)
        edge_mlp_kernel<1><<<nblk, 256, 0, stream>>>(hE, eidx, vff, P1, P2, wbd, w12t, w13t,
                                                     b12, b13, psum, psumsq,
                                                     (float*)d_out, xbf, E);
    else
        edge_mlp_kernel<0><<<nblk, 256, 0, stream>>>(hE, eidx, vff, P1, P2, wbd, w12t, w13t,
                                                     b12, b13, psum, psumsq,
                                                     (float*)d_out, xbf, E);

    bn_stats1<<<64, 256, 0, stream>>>(psum, psumsq, part, nblk);
    bn_stats2<<<1, 128, 0, stream>>>(part, gamma, beta, params, 1.0f / (float)E);

    if (useBf)
        bn_apply_bf16<<<2048, 256, 0, stream>>>(xbf, (float*)d_out, params, E * HID / 8);
    else
        bn_apply_f32<<<2048, 256, 0, stream>>>((float*)d_out, params, E * HID / 4);
}